// Round 7
// baseline (180.194 us; speedup 1.0000x reference)
//
#include <hip/hip_runtime.h>
#include <hip/hip_bf16.h>
#include <cstdint>

#define IN_F   1024
#define OUT_F  1024
#define KTOT   (IN_F + IN_F * 8)      // 9216
#define BATCH  4096

#define BM 128
#define BN 128
#define BK 64
#define NT (KTOT / BK)                // 144 K-steps
#define ROWB (BK * 2)                 // 128 bytes per K-step row
#define BSLOT 16384                   // bytes per B ring slot (BN x BK x 2)

typedef __attribute__((ext_vector_type(8))) __bf16 bf16x8;
typedef __attribute__((ext_vector_type(4))) float  f32x4;
typedef __attribute__((ext_vector_type(8))) short  short8v;

typedef __attribute__((address_space(1))) const uint32_t gu32;
typedef __attribute__((address_space(3))) uint32_t       lu32;

__device__ __forceinline__ void gl_lds16(const void* g, void* l) {
    __builtin_amdgcn_global_load_lds((gu32*)g, (lu32*)l, 16, 0, 0);
}

// float -> bf16 RNE
__device__ __forceinline__ unsigned short f2bf(float f) {
    unsigned int u = __builtin_bit_cast(unsigned int, f);
    return (unsigned short)((u + 0x7fffu + ((u >> 16) & 1u)) >> 16);
}

__device__ __forceinline__ float knot(int i) { return 0.4f * (float)i - 2.2f; }

// ---------------------------------------------------------------------------
// Merged prep: blocks [0,16384) build Act (BATCH x KTOT), blocks [16384,20480)
// build Wb (OUT_F x KTOT).
// ---------------------------------------------------------------------------
__global__ void build_all_kernel(const float* __restrict__ x,
                                 const float* __restrict__ base_w,
                                 const float* __restrict__ spline_w,
                                 const float* __restrict__ scaler,
                                 unsigned short* __restrict__ Act,
                                 unsigned short* __restrict__ Wb) {
    const int bid = blockIdx.x;
    if (bid < 16384) {
        int idx = bid * 256 + threadIdx.x;        // 0 .. 4096*1024-1
        int b = idx >> 10;
        int j = idx & 1023;

        float xv = x[idx];
        float sil = xv * __frcp_rn(1.0f + __expf(-xv));
        Act[(size_t)b * KTOT + j] = f2bf(sil);

        const float r1 = 1.0f / (0.4f + 1e-8f);
        const float r2 = 1.0f / (0.8f + 1e-8f);
        const float r3 = 1.0f / (1.2f + 1e-8f);

        float bas[11];
        #pragma unroll
        for (int i = 0; i < 11; ++i)
            bas[i] = (xv >= knot(i) && xv < knot(i + 1)) ? 1.0f : 0.0f;
        #pragma unroll
        for (int i = 0; i < 10; ++i)
            bas[i] = (xv - knot(i)) * r1 * bas[i] + (knot(i + 2) - xv) * r1 * bas[i + 1];
        #pragma unroll
        for (int i = 0; i < 9; ++i)
            bas[i] = (xv - knot(i)) * r2 * bas[i] + (knot(i + 3) - xv) * r2 * bas[i + 1];
        #pragma unroll
        for (int i = 0; i < 8; ++i)
            bas[i] = (xv - knot(i)) * r3 * bas[i] + (knot(i + 4) - xv) * r3 * bas[i + 1];

        short8v v;
        #pragma unroll
        for (int c = 0; c < 8; ++c) v[c] = (short)f2bf(bas[c]);
        *(short8v*)(Act + (size_t)b * KTOT + IN_F + (size_t)j * 8) = v;
    } else {
        int idx = (bid - 16384) * 256 + threadIdx.x;  // 0 .. 1024*1024-1
        int o = idx >> 10;
        int j = idx & 1023;

        Wb[(size_t)o * KTOT + j] = f2bf(base_w[idx]);

        float s = scaler[idx];
        const float4* sw4 = (const float4*)(spline_w + (size_t)idx * 8);
        float4 w0 = sw4[0], w1 = sw4[1];

        short8v v;
        v[0] = (short)f2bf(w0.x * s); v[1] = (short)f2bf(w0.y * s);
        v[2] = (short)f2bf(w0.z * s); v[3] = (short)f2bf(w0.w * s);
        v[4] = (short)f2bf(w1.x * s); v[5] = (short)f2bf(w1.y * s);
        v[6] = (short)f2bf(w1.z * s); v[7] = (short)f2bf(w1.w * s);
        *(short8v*)(Wb + (size_t)o * KTOT + IN_F + (size_t)j * 8) = v;
    }
}

// ---------------------------------------------------------------------------
// GEMM: C (4096x1024) f32 = Act . Wb^T.  128x128 tile, BK=64.
// r6 was at the LDS-BW ceiling (96 KB/step ~= 1000+ cyc > MFMA 621 cyc).
// NEW (r7): A bypasses LDS — each wave global_load_dwordx4's its own A
// fragments directly into registers (lanes {r,r+16,r+32,r+48} of a frag read
// one contiguous 64B span of row r -> 100% line utilization). A is L2-resident
// per-XCD (r6 partition). Double-buffered 1 iter ahead (~700cyc >> L2 lat).
// LDS carries only B: 16KB write + 32KB read per step (~500 cyc < MFMA 621)
// -> MFMA-bound target.
// vmcnt per iter: 4 A-loads then 2 B-stage gl_lds. Steady outstanding at wait
// = 14; vmcnt(8) drains exactly {B(kt+1), A(kt)}. lgkmcnt(0) before each
// barrier guarantees slot ds_reads drained before any wave's restage lands.
// ---------------------------------------------------------------------------
__global__ __launch_bounds__(512)
void gemm_kernel(const unsigned short* __restrict__ Act,
                 const unsigned short* __restrict__ Wb,
                 float* __restrict__ C) {
    __shared__ char Sm[4 * BSLOT];    // 64 KB B-ring; reused for reduction

    const int tid  = threadIdx.x;
    const int lane = tid & 63;
    const int wave = tid >> 6;        // 0..7
    const int kp   = wave >> 2;       // K-parity 0/1
    const int wr   = (wave >> 1) & 1; // M half
    const int wn   = wave & 1;        // N half

    const int bid  = blockIdx.x;
    const int xcd  = bid & 7;
    const int loc  = bid >> 3;               // 0..31
    const int mblk = xcd * 4 + (loc & 3);    // 4 M-panels per XCD
    const int nblk = loc >> 2;               // all 8 N-panels per XCD
    const int m0 = mblk * BM;
    const int n0 = nblk * BN;

    const int frow = lane & 15;
    const int kgrp = lane >> 4;       // 0..3

    f32x4 acc[4][4] = {};             // 64 VGPRs: 64x64 per wave

    // ---- B staging map: thread t covers 16B at tile offset o / o+8192 ------
    const int o    = tid * 16;                 // 0..8191
    const int row0 = o >> 7;                   // 0..63
    const int colb = o & 127;
    const int scol = colb ^ ((row0 & 7) << 4); // pre-swizzled source column

    const char* bS0 = (const char*)Wb + (size_t)(n0 + row0) * (KTOT * 2) + scol;
    const char* bS1 = bS0 + (size_t)64 * (KTOT * 2);

    #define STAGEB(kt, sl) do {                                      \
        const size_t kk = (size_t)(kt) * ROWB;                       \
        char* d = Sm + (size_t)(sl) * BSLOT + o;                     \
        gl_lds16(bS0 + kk, d);                                       \
        gl_lds16(bS1 + kk, d + 8192);                                \
    } while (0)

    // ---- A direct G->VGPR fragment pointers -------------------------------
    // lane reads 16B at row (m0+wr*64+m*16+frow), byte-col kt*128+kp*64+kgrp*16
    const char* aP[4];
    #pragma unroll
    for (int m = 0; m < 4; ++m)
        aP[m] = (const char*)Act
              + (size_t)(m0 + wr * 64 + m * 16 + frow) * (KTOT * 2)
              + kp * 64 + kgrp * 16;

    bf16x8 aR[2][4], bR[2][4];

    #define LOADA(kt, AB) do {                                       \
        _Pragma("unroll")                                            \
        for (int m = 0; m < 4; ++m)                                  \
            (AB)[m] = *(const bf16x8*)(aP[m] + (size_t)(kt) * ROWB); \
    } while (0)

    const int swz = (lane & 7) << 4;           // fragment row&7 == lane&7
    const int kb  = kp * 64 + kgrp * 16;       // this wave's K=32 half-slice

    #define READB(sl, BB) do {                                               \
        const char* base_ = Sm + (size_t)(sl) * BSLOT;                       \
        _Pragma("unroll")                                                    \
        for (int n = 0; n < 4; ++n) {                                        \
            const int r = wn * 64 + n * 16 + frow;                           \
            (BB)[n] = *(const bf16x8*)(base_ + r * ROWB + (kb ^ swz));       \
        }                                                                    \
    } while (0)

    #define MFMA16(AB, BB) do {                                              \
        __builtin_amdgcn_s_setprio(1);                                       \
        _Pragma("unroll")                                                    \
        for (int m = 0; m < 4; ++m)                                          \
            _Pragma("unroll")                                                \
            for (int n = 0; n < 4; ++n)                                      \
                acc[m][n] = __builtin_amdgcn_mfma_f32_16x16x32_bf16(         \
                                (AB)[m], (BB)[n], acc[m][n], 0, 0, 0);       \
        __builtin_amdgcn_s_setprio(0);                                       \
    } while (0)

    // ---- prologue: A(0) + B(0..2) staged; land A(0)+B(0) ------------------
    LOADA(0, aR[0]);                  // 4 vm
    STAGEB(0, 0);                     // 2 vm
    STAGEB(1, 1);                     // 2 vm
    STAGEB(2, 2);                     // 2 vm
    asm volatile("s_waitcnt vmcnt(4)" ::: "memory");   // A(0),B(0) landed
    __builtin_amdgcn_s_barrier();
    READB(0, bR[0]);

    #define BODY(kt, CB, NB) do {                                            \
        LOADA((kt) + 1, aR[NB]);                                             \
        STAGEB((kt) + 3, ((kt) + 3) & 3);                                    \
        asm volatile("s_waitcnt vmcnt(8) lgkmcnt(0)" ::: "memory");          \
        __builtin_amdgcn_s_barrier();                                        \
        READB(((kt) + 1) & 3, bR[NB]);                                       \
        MFMA16(aR[CB], bR[CB]);                                              \
    } while (0)

    // main: kt = 0..139 (70 pairs); STAGEB(kt+3) <= 142, LOADA(kt+1) <= 140.
    for (int k2 = 0; k2 < 70; ++k2) {
        const int kt = k2 * 2;
        BODY(kt,     0, 1);
        BODY(kt + 1, 1, 0);
    }
    // ---- tail: kt = 140..143 peeled ---------------------------------------
    LOADA(141, aR[1]);
    STAGEB(143, 3);
    asm volatile("s_waitcnt vmcnt(8) lgkmcnt(0)" ::: "memory");
    __builtin_amdgcn_s_barrier();
    READB(1, bR[1]);
    MFMA16(aR[0], bR[0]);                                        // tile 140

    LOADA(142, aR[0]);
    asm volatile("s_waitcnt vmcnt(6) lgkmcnt(0)" ::: "memory");  // B(142),A(141)
    __builtin_amdgcn_s_barrier();
    READB(2, bR[0]);
    MFMA16(aR[1], bR[1]);                                        // tile 141

    LOADA(143, aR[1]);
    asm volatile("s_waitcnt vmcnt(4) lgkmcnt(0)" ::: "memory");  // B(143),A(142)
    __builtin_amdgcn_s_barrier();
    READB(3, bR[1]);
    MFMA16(aR[0], bR[0]);                                        // tile 142

    asm volatile("s_waitcnt vmcnt(0) lgkmcnt(0)" ::: "memory");  // A(143)
    MFMA16(aR[1], bR[1]);                                        // tile 143

    // ---- wave-pair K reduction via LDS, then C store (kp=0 waves) ----------
    __syncthreads();                       // drains all counters; repurpose Sm
    const int pairw = wave & 3;
    if (kp == 1) {
        #pragma unroll
        for (int m = 0; m < 4; ++m)
            #pragma unroll
            for (int n = 0; n < 4; ++n)
                *(f32x4*)(Sm + pairw * 16384 + (m * 4 + n) * 1024 + lane * 16)
                    = acc[m][n];
    }
    __syncthreads();
    if (kp == 0) {
        #pragma unroll
        for (int m = 0; m < 4; ++m) {
            const int row = m0 + wr * 64 + m * 16 + kgrp * 4;
            #pragma unroll
            for (int n = 0; n < 4; ++n) {
                f32x4 t = *(const f32x4*)(Sm + pairw * 16384 + (m * 4 + n) * 1024 + lane * 16);
                f32x4 s = acc[m][n] + t;
                const int col = n0 + wn * 64 + n * 16 + frow;
                float* cp = C + (size_t)row * OUT_F + col;
                #pragma unroll
                for (int r = 0; r < 4; ++r)
                    cp[(size_t)r * OUT_F] = s[r];
            }
        }
    }
    #undef STAGEB
    #undef LOADA
    #undef READB
    #undef MFMA16
    #undef BODY
}

// ---------------------------------------------------------------------------
extern "C" void kernel_launch(void* const* d_in, const int* in_sizes, int n_in,
                              void* d_out, int out_size, void* d_ws, size_t ws_size,
                              hipStream_t stream) {
    const float* x        = (const float*)d_in[0];
    const float* base_w   = (const float*)d_in[1];
    const float* spline_w = (const float*)d_in[2];
    const float* scaler   = (const float*)d_in[3];
    float* out = (float*)d_out;

    const size_t act_bytes = (size_t)BATCH * KTOT * 2;   // 75.5 MB
    const size_t w_bytes   = (size_t)OUT_F * KTOT * 2;   // 18.9 MB
    if (ws_size < act_bytes + w_bytes) return;

    unsigned short* Act = (unsigned short*)d_ws;
    unsigned short* Wb  = (unsigned short*)((char*)d_ws + act_bytes);

    build_all_kernel<<<16384 + 4096, 256, 0, stream>>>(x, base_w, spline_w, scaler, Act, Wb);
    gemm_kernel<<<(BATCH / BM) * (OUT_F / BN), 512, 0, stream>>>(Act, Wb, out);
}

// Round 8
// 127.462 us; speedup vs baseline: 1.4137x; 1.4137x over previous
//
#include <hip/hip_runtime.h>
#include <hip/hip_bf16.h>
#include <cstdint>

#define IN_F   1024
#define OUT_F  1024
#define KTOT   (IN_F + IN_F * 8)      // 9216
#define BATCH  4096

#define BM 128
#define BN 128
#define BK 64
#define NT (KTOT / BK)                // 144 K-steps
#define ROWB (BK * 2)                 // 128 bytes per K-step row (B tiles)
#define BSLOT 16384                   // bytes per B ring slot (BN x BK x 2)
#define A2STEP 16384                  // bytes per [kt] block of an A panel

typedef __attribute__((ext_vector_type(8))) __bf16 bf16x8;
typedef __attribute__((ext_vector_type(4))) float  f32x4;
typedef __attribute__((ext_vector_type(8))) short  short8v;

typedef __attribute__((address_space(1))) const uint32_t gu32;
typedef __attribute__((address_space(3))) uint32_t       lu32;

__device__ __forceinline__ void gl_lds16(const void* g, void* l) {
    __builtin_amdgcn_global_load_lds((gu32*)g, (lu32*)l, 16, 0, 0);
}

// float -> bf16 RNE
__device__ __forceinline__ unsigned short f2bf(float f) {
    unsigned int u = __builtin_bit_cast(unsigned int, f);
    return (unsigned short)((u + 0x7fffu + ((u >> 16) & 1u)) >> 16);
}

__device__ __forceinline__ float knot(int i) { return 0.4f * (float)i - 2.2f; }

// Fragment-major A layout: byte offset of the 16B group holding (b, k), k 8-aligned.
// [mb(32)][kt(144)][kp(2)][g(8)][lane(64)x16B]  with g=(b&127)>>4, frow=b&15,
// lane = kgrp*16+frow, kgrp=(k>>3)&3, kp=(k>>5)&1, kt=k>>6.
__device__ __forceinline__ size_t a2off(int b, int k) {
    const int mb = b >> 7, bb = b & 127;
    const int g = bb >> 4, frow = bb & 15;
    const int kt = k >> 6, kp = (k >> 5) & 1, kg = (k >> 3) & 3;
    return ((size_t)(mb * NT + kt) * 2 + kp) * 8192 + g * 1024 + kg * 256 + frow * 16;
}

// ---------------------------------------------------------------------------
// Merged prep.
// Blocks [0,2048): Act in fragment-major layout. Thread = (b, j8): 8 in-feats.
//   silu of 8 feats -> one 16B group; basis of each feat -> one 16B group.
// Blocks [2048, 6144): Wb row-major (unchanged): [base_w | spline_w*scaler].
// ---------------------------------------------------------------------------
__global__ void build_all_kernel(const float* __restrict__ x,
                                 const float* __restrict__ base_w,
                                 const float* __restrict__ spline_w,
                                 const float* __restrict__ scaler,
                                 unsigned short* __restrict__ Act,
                                 unsigned short* __restrict__ Wb) {
    const int bid = blockIdx.x;
    if (bid < 2048) {
        const int idx = bid * 256 + threadIdx.x;   // 0..524287
        const int b  = idx >> 7;
        const int j8 = idx & 127;

        const float* xp = x + (size_t)b * IN_F + j8 * 8;
        const float4 x0 = *(const float4*)xp;
        const float4 x1 = *(const float4*)(xp + 4);
        float xv[8] = {x0.x, x0.y, x0.z, x0.w, x1.x, x1.y, x1.z, x1.w};

        char* base = (char*)Act;

        short8v sv;
        #pragma unroll
        for (int i = 0; i < 8; ++i) {
            float s = xv[i] * __frcp_rn(1.0f + __expf(-xv[i]));
            sv[i] = (short)f2bf(s);
        }
        *(short8v*)(base + a2off(b, j8 * 8)) = sv;

        const float r1 = 1.0f / (0.4f + 1e-8f);
        const float r2 = 1.0f / (0.8f + 1e-8f);
        const float r3 = 1.0f / (1.2f + 1e-8f);

        #pragma unroll
        for (int i = 0; i < 8; ++i) {
            const float xvi = xv[i];
            float bas[11];
            #pragma unroll
            for (int t = 0; t < 11; ++t)
                bas[t] = (xvi >= knot(t) && xvi < knot(t + 1)) ? 1.0f : 0.0f;
            #pragma unroll
            for (int t = 0; t < 10; ++t)
                bas[t] = (xvi - knot(t)) * r1 * bas[t] + (knot(t + 2) - xvi) * r1 * bas[t + 1];
            #pragma unroll
            for (int t = 0; t < 9; ++t)
                bas[t] = (xvi - knot(t)) * r2 * bas[t] + (knot(t + 3) - xvi) * r2 * bas[t + 1];
            #pragma unroll
            for (int t = 0; t < 8; ++t)
                bas[t] = (xvi - knot(t)) * r3 * bas[t] + (knot(t + 4) - xvi) * r3 * bas[t + 1];

            short8v v;
            #pragma unroll
            for (int c = 0; c < 8; ++c) v[c] = (short)f2bf(bas[c]);
            *(short8v*)(base + a2off(b, IN_F + (j8 * 8 + i) * 8)) = v;
        }
    } else {
        const int idx = (bid - 2048) * 256 + threadIdx.x;  // 0 .. 1024*1024-1
        const int o = idx >> 10;
        const int j = idx & 1023;

        Wb[(size_t)o * KTOT + j] = f2bf(base_w[idx]);

        float s = scaler[idx];
        const float4* sw4 = (const float4*)(spline_w + (size_t)idx * 8);
        float4 w0 = sw4[0], w1 = sw4[1];

        short8v v;
        v[0] = (short)f2bf(w0.x * s); v[1] = (short)f2bf(w0.y * s);
        v[2] = (short)f2bf(w0.z * s); v[3] = (short)f2bf(w0.w * s);
        v[4] = (short)f2bf(w1.x * s); v[5] = (short)f2bf(w1.y * s);
        v[6] = (short)f2bf(w1.z * s); v[7] = (short)f2bf(w1.w * s);
        *(short8v*)(Wb + (size_t)o * KTOT + IN_F + (size_t)j * 8) = v;
    }
}

// ---------------------------------------------------------------------------
// GEMM: C (4096x1024) f32 = Act . Wb^T.  128x128 tile, BK=64.
// A is fragment-major in global: each wave's A fragment = ONE contiguous
// 1024B burst (coalesced, 1 base reg + imm offsets) G->VGPR, double-buffered
// one iter ahead; A never touches LDS (r7's 16-line-gather fixed by layout).
// LDS carries only B (16KB write + 32KB read per step ~= 500cyc < MFMA 621).
// vmcnt per BODY: 4 A + 2 B-stage; steady vmcnt(8) drains {B(kt+1), A(kt)}.
// lgkmcnt(0) before each barrier: slot ds_reads drained before restage.
// ---------------------------------------------------------------------------
__global__ __launch_bounds__(512)
void gemm_kernel(const unsigned short* __restrict__ Act,
                 const unsigned short* __restrict__ Wb,
                 float* __restrict__ C) {
    __shared__ char Sm[4 * BSLOT];    // 64 KB B-ring; reused for reduction

    const int tid  = threadIdx.x;
    const int lane = tid & 63;
    const int wave = tid >> 6;        // 0..7
    const int kp   = wave >> 2;       // K-parity 0/1
    const int wr   = (wave >> 1) & 1; // M half
    const int wn   = wave & 1;        // N half

    const int bid  = blockIdx.x;
    const int xcd  = bid & 7;
    const int loc  = bid >> 3;               // 0..31
    const int mblk = xcd * 4 + (loc & 3);    // 4 M-panels per XCD
    const int nblk = loc >> 2;               // all 8 N-panels per XCD
    const int m0 = mblk * BM;
    const int n0 = nblk * BN;

    const int frow = lane & 15;
    const int kgrp = lane >> 4;       // 0..3

    f32x4 acc[4][4] = {};             // 64 VGPRs: 64x64 per wave

    // ---- B staging map: thread t covers 16B at tile offset o / o+8192 ------
    const int o    = tid * 16;                 // 0..8191
    const int row0 = o >> 7;                   // 0..63
    const int colb = o & 127;
    const int scol = colb ^ ((row0 & 7) << 4); // pre-swizzled source column

    const char* bS0 = (const char*)Wb + (size_t)(n0 + row0) * (KTOT * 2) + scol;
    const char* bS1 = bS0 + (size_t)64 * (KTOT * 2);

    #define STAGEB(kt, sl) do {                                      \
        const size_t kk = (size_t)(kt) * ROWB;                       \
        char* d = Sm + (size_t)(sl) * BSLOT + o;                     \
        gl_lds16(bS0 + kk, d);                                       \
        gl_lds16(bS1 + kk, d + 8192);                                \
    } while (0)

    // ---- A fragment-major base: frag m at +m*1024, step kt at +kt*16384 ----
    const char* aBase = (const char*)Act
        + (size_t)mblk * NT * A2STEP + (size_t)kp * 8192
        + (wr * 4) * 1024 + lane * 16;

    bf16x8 aR[2][4], bR[2][4];

    #define LOADA(kt, AB) do {                                       \
        const char* p_ = aBase + (size_t)(kt) * A2STEP;              \
        _Pragma("unroll")                                            \
        for (int m = 0; m < 4; ++m)                                  \
            (AB)[m] = *(const bf16x8*)(p_ + m * 1024);               \
    } while (0)

    const int swz = (lane & 7) << 4;           // B fragment row&7 == lane&7
    const int kb  = kp * 64 + kgrp * 16;       // this wave's K=32 half-slice

    #define READB(sl, BB) do {                                               \
        const char* base_ = Sm + (size_t)(sl) * BSLOT;                       \
        _Pragma("unroll")                                                    \
        for (int n = 0; n < 4; ++n) {                                        \
            const int r = wn * 64 + n * 16 + frow;                           \
            (BB)[n] = *(const bf16x8*)(base_ + r * ROWB + (kb ^ swz));       \
        }                                                                    \
    } while (0)

    #define MFMA16(AB, BB) do {                                              \
        __builtin_amdgcn_s_setprio(1);                                       \
        _Pragma("unroll")                                                    \
        for (int m = 0; m < 4; ++m)                                          \
            _Pragma("unroll")                                                \
            for (int n = 0; n < 4; ++n)                                      \
                acc[m][n] = __builtin_amdgcn_mfma_f32_16x16x32_bf16(         \
                                (AB)[m], (BB)[n], acc[m][n], 0, 0, 0);       \
        __builtin_amdgcn_s_setprio(0);                                       \
    } while (0)

    // ---- prologue: A(0) + B(0..2) staged; land A(0)+B(0) ------------------
    LOADA(0, aR[0]);                  // 4 vm
    STAGEB(0, 0);                     // 2 vm
    STAGEB(1, 1);                     // 2 vm
    STAGEB(2, 2);                     // 2 vm
    asm volatile("s_waitcnt vmcnt(4)" ::: "memory");   // A(0),B(0) landed
    __builtin_amdgcn_s_barrier();
    READB(0, bR[0]);

    #define BODY(kt, CB, NB) do {                                            \
        LOADA((kt) + 1, aR[NB]);                                             \
        STAGEB((kt) + 3, ((kt) + 3) & 3);                                    \
        asm volatile("s_waitcnt vmcnt(8) lgkmcnt(0)" ::: "memory");          \
        __builtin_amdgcn_s_barrier();                                        \
        READB(((kt) + 1) & 3, bR[NB]);                                       \
        MFMA16(aR[CB], bR[CB]);                                              \
    } while (0)

    // main: kt = 0..139 (70 pairs); STAGEB(kt+3) <= 142, LOADA(kt+1) <= 140.
    for (int k2 = 0; k2 < 70; ++k2) {
        const int kt = k2 * 2;
        BODY(kt,     0, 1);
        BODY(kt + 1, 1, 0);
    }
    // ---- tail: kt = 140..143 peeled ---------------------------------------
    LOADA(141, aR[1]);
    STAGEB(143, 3);
    asm volatile("s_waitcnt vmcnt(8) lgkmcnt(0)" ::: "memory");
    __builtin_amdgcn_s_barrier();
    READB(1, bR[1]);
    MFMA16(aR[0], bR[0]);                                        // tile 140

    LOADA(142, aR[0]);
    asm volatile("s_waitcnt vmcnt(6) lgkmcnt(0)" ::: "memory");  // B(142),A(141)
    __builtin_amdgcn_s_barrier();
    READB(2, bR[0]);
    MFMA16(aR[1], bR[1]);                                        // tile 141

    LOADA(143, aR[1]);
    asm volatile("s_waitcnt vmcnt(4) lgkmcnt(0)" ::: "memory");  // B(143),A(142)
    __builtin_amdgcn_s_barrier();
    READB(3, bR[1]);
    MFMA16(aR[0], bR[0]);                                        // tile 142

    asm volatile("s_waitcnt vmcnt(0) lgkmcnt(0)" ::: "memory");  // A(143)
    MFMA16(aR[1], bR[1]);                                        // tile 143

    // ---- wave-pair K reduction via LDS, then C store (kp=0 waves) ----------
    __syncthreads();                       // drains all counters; repurpose Sm
    const int pairw = wave & 3;
    if (kp == 1) {
        #pragma unroll
        for (int m = 0; m < 4; ++m)
            #pragma unroll
            for (int n = 0; n < 4; ++n)
                *(f32x4*)(Sm + pairw * 16384 + (m * 4 + n) * 1024 + lane * 16)
                    = acc[m][n];
    }
    __syncthreads();
    if (kp == 0) {
        #pragma unroll
        for (int m = 0; m < 4; ++m) {
            const int row = m0 + wr * 64 + m * 16 + kgrp * 4;
            #pragma unroll
            for (int n = 0; n < 4; ++n) {
                f32x4 t = *(const f32x4*)(Sm + pairw * 16384 + (m * 4 + n) * 1024 + lane * 16);
                f32x4 s = acc[m][n] + t;
                const int col = n0 + wn * 64 + n * 16 + frow;
                float* cp = C + (size_t)row * OUT_F + col;
                #pragma unroll
                for (int r = 0; r < 4; ++r)
                    cp[(size_t)r * OUT_F] = s[r];
            }
        }
    }
    #undef STAGEB
    #undef LOADA
    #undef READB
    #undef MFMA16
    #undef BODY
}

// ---------------------------------------------------------------------------
extern "C" void kernel_launch(void* const* d_in, const int* in_sizes, int n_in,
                              void* d_out, int out_size, void* d_ws, size_t ws_size,
                              hipStream_t stream) {
    const float* x        = (const float*)d_in[0];
    const float* base_w   = (const float*)d_in[1];
    const float* spline_w = (const float*)d_in[2];
    const float* scaler   = (const float*)d_in[3];
    float* out = (float*)d_out;

    const size_t act_bytes = (size_t)BATCH * KTOT * 2;   // 75.5 MB
    const size_t w_bytes   = (size_t)OUT_F * KTOT * 2;   // 18.9 MB
    if (ws_size < act_bytes + w_bytes) return;

    unsigned short* Act = (unsigned short*)d_ws;
    unsigned short* Wb  = (unsigned short*)((char*)d_ws + act_bytes);

    build_all_kernel<<<2048 + 4096, 256, 0, stream>>>(x, base_w, spline_w, scaler, Act, Wb);
    gemm_kernel<<<(BATCH / BM) * (OUT_F / BN), 512, 0, stream>>>(Act, Wb, out);
}

// Round 9
// 125.803 us; speedup vs baseline: 1.4324x; 1.0132x over previous
//
#include <hip/hip_runtime.h>
#include <hip/hip_bf16.h>
#include <cstdint>

#define IN_F   1024
#define OUT_F  1024
#define KTOT   (IN_F + IN_F * 8)      // 9216
#define BATCH  4096

#define BM 128
#define BN 128
#define BK 64
#define NT (KTOT / BK)                // 144 K-steps total
#define NTS (NT / 2)                  // 72 K-steps per split-K block
#define ROWB (BK * 2)                 // 128 bytes per K-step row (B tiles)
#define BSLOT 16384                   // bytes per B ring slot (BN x BK x 2)
#define A2STEP 16384                  // bytes per [kt] block of an A panel

typedef __attribute__((ext_vector_type(8))) __bf16 bf16x8;
typedef __attribute__((ext_vector_type(4))) float  f32x4;
typedef __attribute__((ext_vector_type(8))) short  short8v;

typedef __attribute__((address_space(1))) const uint32_t gu32;
typedef __attribute__((address_space(3))) uint32_t       lu32;

__device__ __forceinline__ void gl_lds16(const void* g, void* l) {
    __builtin_amdgcn_global_load_lds((gu32*)g, (lu32*)l, 16, 0, 0);
}

// float -> bf16 RNE
__device__ __forceinline__ unsigned short f2bf(float f) {
    unsigned int u = __builtin_bit_cast(unsigned int, f);
    return (unsigned short)((u + 0x7fffu + ((u >> 16) & 1u)) >> 16);
}

__device__ __forceinline__ float knot(int i) { return 0.4f * (float)i - 2.2f; }

// ---------------------------------------------------------------------------
// Merged prep, write-coalesced.
// Blocks [0,512): Act in fragment-major layout. Block = (mb, p): stages
//   x[mb*128..+128][64p..+64] in LDS (padded), then emits silu kt-block p and
//   basis kt-blocks 16+8p..+8 in OUTPUT order -> every wave writes contiguous
//   1KB (r8 prep scattered 16B chunks; write fill was the prep cost).
// Blocks [512, 4608): Wb row-major: [base_w | spline_w*scaler] (unchanged).
// ---------------------------------------------------------------------------
__global__ __launch_bounds__(256)
void build_all_kernel(const float* __restrict__ x,
                      const float* __restrict__ base_w,
                      const float* __restrict__ spline_w,
                      const float* __restrict__ scaler,
                      unsigned short* __restrict__ Act,
                      unsigned short* __restrict__ Wb) {
    const int bid = blockIdx.x;
    const int tid = threadIdx.x;
    if (bid < 512) {
        __shared__ float xs[128][65];
        const int mb = bid >> 4;
        const int p  = bid & 15;

        // stage x-patch coalesced: 8192 floats, 32 per thread
        const float* xbase = x + (size_t)mb * 128 * IN_F + p * 64;
        #pragma unroll
        for (int i = 0; i < 32; ++i) {
            const int f = i * 256 + tid;
            const int r = f >> 6, c = f & 63;
            xs[r][c] = xbase[(size_t)r * IN_F + c];
        }
        __syncthreads();

        char* outS = (char*)Act + (size_t)(mb * NT + p) * A2STEP;
        char* outB = (char*)Act + (size_t)(mb * NT + 16 + p * 8) * A2STEP;

        const float r1 = 1.0f / (0.4f + 1e-8f);
        const float r2 = 1.0f / (0.8f + 1e-8f);
        const float r3 = 1.0f / (1.2f + 1e-8f);

        // silu kt-block p: 1024 chunks, 4 per thread, write-coalesced
        #pragma unroll
        for (int it = 0; it < 4; ++it) {
            const int ch = it * 256 + tid;
            const int kp = ch >> 9, g = (ch >> 6) & 7, kg = (ch >> 4) & 3, fr = ch & 15;
            const int b = g * 16 + fr;
            const int c0 = kp * 32 + kg * 8;
            short8v v;
            #pragma unroll
            for (int u = 0; u < 8; ++u) {
                const float xv = xs[b][c0 + u];
                v[u] = (short)f2bf(xv * __frcp_rn(1.0f + __expf(-xv)));
            }
            *(short8v*)(outS + kp * 8192 + g * 1024 + kg * 256 + fr * 16) = v;
        }

        // basis kt-blocks: 8192 chunks (one per (b, j)), 32 per thread
        #pragma unroll
        for (int it = 0; it < 32; ++it) {
            const int ch  = it * 256 + tid;
            const int ktl = ch >> 10;
            const int rest = ch & 1023;
            const int kp = rest >> 9, g = (rest >> 6) & 7, kg = (rest >> 4) & 3, fr = rest & 15;
            const int b  = g * 16 + fr;
            const int jc = 8 * ktl + 4 * kp + kg;    // col within the 64-patch
            const float xv = xs[b][jc];

            float bas[11];
            #pragma unroll
            for (int t = 0; t < 11; ++t)
                bas[t] = (xv >= knot(t) && xv < knot(t + 1)) ? 1.0f : 0.0f;
            #pragma unroll
            for (int t = 0; t < 10; ++t)
                bas[t] = (xv - knot(t)) * r1 * bas[t] + (knot(t + 2) - xv) * r1 * bas[t + 1];
            #pragma unroll
            for (int t = 0; t < 9; ++t)
                bas[t] = (xv - knot(t)) * r2 * bas[t] + (knot(t + 3) - xv) * r2 * bas[t + 1];
            #pragma unroll
            for (int t = 0; t < 8; ++t)
                bas[t] = (xv - knot(t)) * r3 * bas[t] + (knot(t + 4) - xv) * r3 * bas[t + 1];

            short8v v;
            #pragma unroll
            for (int c = 0; c < 8; ++c) v[c] = (short)f2bf(bas[c]);
            *(short8v*)(outB + (size_t)ktl * A2STEP
                        + kp * 8192 + g * 1024 + kg * 256 + fr * 16) = v;
        }
    } else {
        const int idx = (bid - 512) * 256 + tid;      // 0 .. 1024*1024-1
        const int o = idx >> 10;
        const int j = idx & 1023;

        Wb[(size_t)o * KTOT + j] = f2bf(base_w[idx]);

        float s = scaler[idx];
        const float4* sw4 = (const float4*)(spline_w + (size_t)idx * 8);
        float4 w0 = sw4[0], w1 = sw4[1];

        short8v v;
        v[0] = (short)f2bf(w0.x * s); v[1] = (short)f2bf(w0.y * s);
        v[2] = (short)f2bf(w0.z * s); v[3] = (short)f2bf(w0.w * s);
        v[4] = (short)f2bf(w1.x * s); v[5] = (short)f2bf(w1.y * s);
        v[6] = (short)f2bf(w1.z * s); v[7] = (short)f2bf(w1.w * s);
        *(short8v*)(Wb + (size_t)o * KTOT + IN_F + (size_t)j * 8) = v;
    }
}

// ---------------------------------------------------------------------------
// Split-K GEMM: grid 512 = 2 blocks/CU (the TLP r3-r8 lacked; LDS 64KB/block).
// Each block computes a 128x128 tile over HALF of K (72 steps): s=0 -> C,
// s=1 -> P1; add_kernel sums. Structure = r8 verbatim (A fragment-major
// direct G->VGPR, B-only LDS ring-4, counted vmcnt(8), kp-split waves).
// ---------------------------------------------------------------------------
__global__ __launch_bounds__(512)
void gemm_kernel(const unsigned short* __restrict__ Act,
                 const unsigned short* __restrict__ Wb,
                 float* __restrict__ C,
                 float* __restrict__ P1) {
    __shared__ char Sm[4 * BSLOT];    // 64 KB B-ring; reused for reduction

    const int tid  = threadIdx.x;
    const int lane = tid & 63;
    const int wave = tid >> 6;        // 0..7
    const int kp   = wave >> 2;       // K-parity 0/1
    const int wr   = (wave >> 1) & 1; // M half
    const int wn   = wave & 1;        // N half

    const int bid  = blockIdx.x;      // 0..511
    const int xcd  = bid & 7;
    const int s    = (bid >> 3) & 1;  // split-K half
    const int loc  = bid >> 4;        // 0..31
    const int mblk = xcd * 4 + (loc & 3);
    const int nblk = loc >> 2;
    const int m0 = mblk * BM;
    const int n0 = nblk * BN;

    const int frow = lane & 15;
    const int kgrp = lane >> 4;

    float* Cout = s ? P1 : C;

    f32x4 acc[4][4] = {};

    // ---- B staging map ----------------------------------------------------
    const int o    = tid * 16;
    const int row0 = o >> 7;
    const int colb = o & 127;
    const int scol = colb ^ ((row0 & 7) << 4);

    const char* bS0 = (const char*)Wb + (size_t)(n0 + row0) * (KTOT * 2) + scol
                    + (size_t)s * NTS * ROWB;
    const char* bS1 = bS0 + (size_t)64 * (KTOT * 2);

    #define STAGEB(kt, sl) do {                                      \
        const size_t kk = (size_t)(kt) * ROWB;                       \
        char* d = Sm + (size_t)(sl) * BSLOT + o;                     \
        gl_lds16(bS0 + kk, d);                                       \
        gl_lds16(bS1 + kk, d + 8192);                                \
    } while (0)

    // ---- A fragment-major base (k-offset by split half) -------------------
    const char* aBase = (const char*)Act
        + (size_t)(mblk * NT + s * NTS) * A2STEP + (size_t)kp * 8192
        + (wr * 4) * 1024 + lane * 16;

    bf16x8 aR[2][4], bR[2][4];

    #define LOADA(kt, AB) do {                                       \
        const char* p_ = aBase + (size_t)(kt) * A2STEP;              \
        _Pragma("unroll")                                            \
        for (int m = 0; m < 4; ++m)                                  \
            (AB)[m] = *(const bf16x8*)(p_ + m * 1024);               \
    } while (0)

    const int swz = (lane & 7) << 4;
    const int kb  = kp * 64 + kgrp * 16;

    #define READB(sl, BB) do {                                               \
        const char* base_ = Sm + (size_t)(sl) * BSLOT;                       \
        _Pragma("unroll")                                                    \
        for (int n = 0; n < 4; ++n) {                                        \
            const int r = wn * 64 + n * 16 + frow;                           \
            (BB)[n] = *(const bf16x8*)(base_ + r * ROWB + (kb ^ swz));       \
        }                                                                    \
    } while (0)

    #define MFMA16(AB, BB) do {                                              \
        __builtin_amdgcn_s_setprio(1);                                       \
        _Pragma("unroll")                                                    \
        for (int m = 0; m < 4; ++m)                                          \
            _Pragma("unroll")                                                \
            for (int n = 0; n < 4; ++n)                                      \
                acc[m][n] = __builtin_amdgcn_mfma_f32_16x16x32_bf16(         \
                                (AB)[m], (BB)[n], acc[m][n], 0, 0, 0);       \
        __builtin_amdgcn_s_setprio(0);                                       \
    } while (0)

    // ---- prologue ---------------------------------------------------------
    LOADA(0, aR[0]);
    STAGEB(0, 0);
    STAGEB(1, 1);
    STAGEB(2, 2);
    asm volatile("s_waitcnt vmcnt(4)" ::: "memory");   // A(0),B(0) landed
    __builtin_amdgcn_s_barrier();
    READB(0, bR[0]);

    #define BODY(kt, CB, NB) do {                                            \
        LOADA((kt) + 1, aR[NB]);                                             \
        STAGEB((kt) + 3, ((kt) + 3) & 3);                                    \
        asm volatile("s_waitcnt vmcnt(8) lgkmcnt(0)" ::: "memory");          \
        __builtin_amdgcn_s_barrier();                                        \
        READB(((kt) + 1) & 3, bR[NB]);                                       \
        MFMA16(aR[CB], bR[CB]);                                              \
    } while (0)

    // main: kt = 0..67 (34 pairs); STAGEB(kt+3) <= 70, LOADA(kt+1) <= 68.
    for (int k2 = 0; k2 < 34; ++k2) {
        const int kt = k2 * 2;
        BODY(kt,     0, 1);
        BODY(kt + 1, 1, 0);
    }
    // ---- tail: kt = 68..71 ------------------------------------------------
    LOADA(69, aR[1]);
    STAGEB(71, 3);
    asm volatile("s_waitcnt vmcnt(8) lgkmcnt(0)" ::: "memory");
    __builtin_amdgcn_s_barrier();
    READB(1, bR[1]);
    MFMA16(aR[0], bR[0]);                                        // 68

    LOADA(70, aR[0]);
    asm volatile("s_waitcnt vmcnt(6) lgkmcnt(0)" ::: "memory");
    __builtin_amdgcn_s_barrier();
    READB(2, bR[0]);
    MFMA16(aR[1], bR[1]);                                        // 69

    LOADA(71, aR[1]);
    asm volatile("s_waitcnt vmcnt(4) lgkmcnt(0)" ::: "memory");
    __builtin_amdgcn_s_barrier();
    READB(3, bR[1]);
    MFMA16(aR[0], bR[0]);                                        // 70

    asm volatile("s_waitcnt vmcnt(0) lgkmcnt(0)" ::: "memory");
    MFMA16(aR[1], bR[1]);                                        // 71

    // ---- wave-pair K reduction via LDS, then store (kp=0 waves) -----------
    __syncthreads();
    const int pairw = wave & 3;
    if (kp == 1) {
        #pragma unroll
        for (int m = 0; m < 4; ++m)
            #pragma unroll
            for (int n = 0; n < 4; ++n)
                *(f32x4*)(Sm + pairw * 16384 + (m * 4 + n) * 1024 + lane * 16)
                    = acc[m][n];
    }
    __syncthreads();
    if (kp == 0) {
        #pragma unroll
        for (int m = 0; m < 4; ++m) {
            const int row = m0 + wr * 64 + m * 16 + kgrp * 4;
            #pragma unroll
            for (int n = 0; n < 4; ++n) {
                f32x4 t = *(const f32x4*)(Sm + pairw * 16384 + (m * 4 + n) * 1024 + lane * 16);
                f32x4 v = acc[m][n] + t;
                const int col = n0 + wn * 64 + n * 16 + frow;
                float* cp = Cout + (size_t)row * OUT_F + col;
                #pragma unroll
                for (int r = 0; r < 4; ++r)
                    cp[(size_t)r * OUT_F] = v[r];
            }
        }
    }
    #undef STAGEB
    #undef LOADA
    #undef READB
    #undef MFMA16
    #undef BODY
}

// ---------------------------------------------------------------------------
__global__ __launch_bounds__(256)
void add_kernel(float* __restrict__ out, const float* __restrict__ p1) {
    const size_t i = (size_t)blockIdx.x * 256 + threadIdx.x;
    float4 a = ((const float4*)out)[i];
    float4 b = ((const float4*)p1)[i];
    a.x += b.x; a.y += b.y; a.z += b.z; a.w += b.w;
    ((float4*)out)[i] = a;
}

// ---------------------------------------------------------------------------
extern "C" void kernel_launch(void* const* d_in, const int* in_sizes, int n_in,
                              void* d_out, int out_size, void* d_ws, size_t ws_size,
                              hipStream_t stream) {
    const float* x        = (const float*)d_in[0];
    const float* base_w   = (const float*)d_in[1];
    const float* spline_w = (const float*)d_in[2];
    const float* scaler   = (const float*)d_in[3];
    float* out = (float*)d_out;

    const size_t act_bytes = (size_t)BATCH * KTOT * 2;        // 75.5 MB
    const size_t w_bytes   = (size_t)OUT_F * KTOT * 2;        // 18.9 MB
    const size_t p1_bytes  = (size_t)BATCH * OUT_F * 4;       // 16.8 MB
    if (ws_size < act_bytes + w_bytes + p1_bytes) return;

    unsigned short* Act = (unsigned short*)d_ws;
    unsigned short* Wb  = (unsigned short*)((char*)d_ws + act_bytes);
    float*          P1  = (float*)((char*)d_ws + act_bytes + w_bytes);

    build_all_kernel<<<512 + 4096, 256, 0, stream>>>(x, base_w, spline_w, scaler, Act, Wb);
    gemm_kernel<<<512, 512, 0, stream>>>(Act, Wb, out, P1);
    add_kernel<<<(BATCH * OUT_F) / (256 * 4), 256, 0, stream>>>(out, P1);
}

// Round 10
// 115.265 us; speedup vs baseline: 1.5633x; 1.0914x over previous
//
#include <hip/hip_runtime.h>
#include <hip/hip_bf16.h>
#include <cstdint>

#define IN_F   1024
#define OUT_F  1024
#define KTOT   9216
#define BATCH  4096

#define NTK    288            // total BK=32 K-steps
#define PSTEP  8192           // bytes per (128-row panel, kt32) fragment block
#define SLOT_B 32768          // ring slot: A 16K | B 16K
#define BM 256
#define BN 256

typedef __attribute__((ext_vector_type(8))) __bf16 bf16x8;
typedef __attribute__((ext_vector_type(4))) float  f32x4;
typedef __attribute__((ext_vector_type(8))) short  short8v;

typedef __attribute__((address_space(1))) const uint32_t gu32;
typedef __attribute__((address_space(3))) uint32_t       lu32;

__device__ __forceinline__ void gl_lds16(const void* g, void* l) {
    __builtin_amdgcn_global_load_lds((gu32*)g, (lu32*)l, 16, 0, 0);
}

__device__ __forceinline__ unsigned short f2bf(float f) {
    unsigned int u = __builtin_bit_cast(unsigned int, f);
    return (unsigned short)((u + 0x7fffu + ((u >> 16) & 1u)) >> 16);
}

__device__ __forceinline__ float knot(int i) { return 0.4f * (float)i - 2.2f; }

// ---------------------------------------------------------------------------
// Fragment-major layout (both Act and Wb):
//   byte = ((panel128 * 288 + kt32) * 8192) + g*1024 + (kgrp*16 + frow)*16
// where panel128 = row>>7, g = (row&127)>>4, frow = row&15,
//       kt32 = k>>5, kgrp = (k>>3)&3.  One 1KB unit = one MFMA fragment.
// ---------------------------------------------------------------------------

// ---------------------------------------------------------------------------
// Prep. Blocks [0,512): Act (r9-verbatim coalesced path; emits exactly the
// layout above). [512,1024): Wb base part. [1024,5120): Wb spline part.
// ---------------------------------------------------------------------------
__global__ __launch_bounds__(256)
void build_all_kernel(const float* __restrict__ x,
                      const float* __restrict__ base_w,
                      const float* __restrict__ spline_w,
                      const float* __restrict__ scaler,
                      unsigned short* __restrict__ Act,
                      unsigned short* __restrict__ Wb) {
    const int bid = blockIdx.x;
    const int tid = threadIdx.x;
    if (bid < 512) {
        // ---- Act: block = (mb 128-row panel, p 64-col patch) ----
        __shared__ float xs[128][65];
        const int mb = bid >> 4;
        const int p  = bid & 15;

        const float* xbase = x + (size_t)mb * 128 * IN_F + p * 64;
        #pragma unroll
        for (int i = 0; i < 32; ++i) {
            const int f = i * 256 + tid;
            const int rr = f >> 6, c = f & 63;
            xs[rr][c] = xbase[(size_t)rr * IN_F + c];
        }
        __syncthreads();

        char* outS = (char*)Act + (size_t)(mb * 144 + p) * 16384;
        char* outB = (char*)Act + (size_t)(mb * 144 + 16 + p * 8) * 16384;

        const float r1 = 1.0f / (0.4f + 1e-8f);
        const float r2 = 1.0f / (0.8f + 1e-8f);
        const float r3 = 1.0f / (1.2f + 1e-8f);

        // silu kt-block: 1024 chunks, write-coalesced
        #pragma unroll
        for (int it = 0; it < 4; ++it) {
            const int ch = it * 256 + tid;
            const int kp = ch >> 9, g = (ch >> 6) & 7, kg = (ch >> 4) & 3, fr = ch & 15;
            const int b = g * 16 + fr;
            const int c0 = kp * 32 + kg * 8;
            short8v v;
            #pragma unroll
            for (int u = 0; u < 8; ++u) {
                const float xv = xs[b][c0 + u];
                v[u] = (short)f2bf(xv * __frcp_rn(1.0f + __expf(-xv)));
            }
            *(short8v*)(outS + kp * 8192 + g * 1024 + kg * 256 + fr * 16) = v;
        }

        // basis chunks
        #pragma unroll
        for (int it = 0; it < 32; ++it) {
            const int ch  = it * 256 + tid;
            const int ktl = ch >> 10;
            const int rest = ch & 1023;
            const int kp = rest >> 9, g = (rest >> 6) & 7, kg = (rest >> 4) & 3, fr = rest & 15;
            const int b  = g * 16 + fr;
            const int jc = 8 * ktl + 4 * kp + kg;
            const float xv = xs[b][jc];

            float bas[11];
            #pragma unroll
            for (int t = 0; t < 11; ++t)
                bas[t] = (xv >= knot(t) && xv < knot(t + 1)) ? 1.0f : 0.0f;
            #pragma unroll
            for (int t = 0; t < 10; ++t)
                bas[t] = (xv - knot(t)) * r1 * bas[t] + (knot(t + 2) - xv) * r1 * bas[t + 1];
            #pragma unroll
            for (int t = 0; t < 9; ++t)
                bas[t] = (xv - knot(t)) * r2 * bas[t] + (knot(t + 3) - xv) * r2 * bas[t + 1];
            #pragma unroll
            for (int t = 0; t < 8; ++t)
                bas[t] = (xv - knot(t)) * r3 * bas[t] + (knot(t + 4) - xv) * r3 * bas[t + 1];

            short8v v;
            #pragma unroll
            for (int c = 0; c < 8; ++c) v[c] = (short)f2bf(bas[c]);
            *(short8v*)(outB + (size_t)ktl * 16384
                        + kp * 8192 + g * 1024 + kg * 256 + fr * 16) = v;
        }
    } else if (bid < 1024) {
        // ---- Wb base part: chunk = one fragment 16B unit ----
        const int bw = bid - 512;                 // 0..511
        const int nb = bw >> 6, kt = (bw >> 1) & 31, half = bw & 1;
        const int g = half * 4 + (tid >> 6);
        const int lane = tid & 63;
        const int kgrp = lane >> 4, frow = lane & 15;
        const int oo = nb * 128 + g * 16 + frow;
        const int jb = kt * 32 + kgrp * 8;

        const float4 w0 = *(const float4*)(base_w + (size_t)oo * 1024 + jb);
        const float4 w1 = *(const float4*)(base_w + (size_t)oo * 1024 + jb + 4);
        short8v v;
        v[0] = (short)f2bf(w0.x); v[1] = (short)f2bf(w0.y);
        v[2] = (short)f2bf(w0.z); v[3] = (short)f2bf(w0.w);
        v[4] = (short)f2bf(w1.x); v[5] = (short)f2bf(w1.y);
        v[6] = (short)f2bf(w1.z); v[7] = (short)f2bf(w1.w);
        *(short8v*)((char*)Wb + (size_t)(nb * NTK + kt) * PSTEP
                    + g * 1024 + lane * 16) = v;
    } else {
        // ---- Wb spline part ----
        const int bw = bid - 1024;                // 0..4095
        const int nb = bw >> 9, kt2 = (bw >> 1) & 255, half = bw & 1;
        const int kt = 32 + kt2;
        const int g = half * 4 + (tid >> 6);
        const int lane = tid & 63;
        const int kgrp = lane >> 4, frow = lane & 15;
        const int oo = nb * 128 + g * 16 + frow;
        const int j  = kt2 * 4 + kgrp;

        const float s = scaler[(size_t)oo * 1024 + j];
        const float* sp = spline_w + ((size_t)oo * 1024 + j) * 8;
        const float4 w0 = *(const float4*)sp;
        const float4 w1 = *(const float4*)(sp + 4);
        short8v v;
        v[0] = (short)f2bf(w0.x * s); v[1] = (short)f2bf(w0.y * s);
        v[2] = (short)f2bf(w0.z * s); v[3] = (short)f2bf(w0.w * s);
        v[4] = (short)f2bf(w1.x * s); v[5] = (short)f2bf(w1.y * s);
        v[6] = (short)f2bf(w1.z * s); v[7] = (short)f2bf(w1.w * s);
        *(short8v*)((char*)Wb + (size_t)(nb * NTK + kt) * PSTEP
                    + g * 1024 + lane * 16) = v;
    }
}

// ---------------------------------------------------------------------------
// 256x256-tile GEMM, BK=32, split-K (adaptive nsplit from grid size).
// 8 waves = 4(M) x 2(N), 64x128 per wave, acc 4x8 f32x4, no cross-wave
// reduction. Fragment-major A/B: staging is 4 linear gl_lds16/thread; all
// ds_read_b128 are base + lane*16 (contiguous 1KB) -> zero bank conflicts,
// no swizzle. Ring-4 LDS (4x32KB), depth-2 staging, r6-verbatim counted
// vmcnt(8)+lgkmcnt(0)+barrier schedule (4 ops/stage: 12 outstanding -> 8
// drains exactly tile kt). Rationale: r6-r9 pinned at ~30 B/cyc/CU VMEM
// return; 256^2 needs only 32KB per 1242 cyc of MFMA (26 B/cyc) -> MFMA-bound.
// ---------------------------------------------------------------------------
__global__ __launch_bounds__(512)
void gemm_kernel(const unsigned short* __restrict__ Act,
                 const unsigned short* __restrict__ Wb,
                 float* __restrict__ C, float* __restrict__ P,
                 int ksteps) {
    __shared__ char Sm[4 * SLOT_B];   // 128 KB

    const int tid  = threadIdx.x;
    const int lane = tid & 63;
    const int wave = tid >> 6;
    const int wr   = wave >> 1;       // 0..3 (64-row slice)
    const int wn   = wave & 1;        // 0..1 (128-col half)

    const int bid  = blockIdx.x;
    const int xcd  = bid & 7;
    const int rr_  = bid >> 3;
    const int mtile = xcd * 2 + (rr_ & 1);   // A panels XCD-private
    const int ntile = (rr_ >> 1) & 3;
    const int s     = rr_ >> 3;              // split-K index

    const int frow = lane & 15;
    const int kgrp = lane >> 4;

    float* Cout = (s == 0) ? C : (P + (size_t)(s - 1) * ((size_t)BATCH * OUT_F));

    f32x4 acc[4][8] = {};             // 128 VGPRs

    const int o = tid * 16;           // staging offset, 512 threads x 16B = 8KB
    const size_t ktbase = (size_t)s * ksteps;

    const char* aLo = (const char*)Act + ((size_t)(mtile * 2) * NTK + ktbase) * PSTEP + o;
    const char* aHi = aLo + (size_t)NTK * PSTEP;
    const char* bLo = (const char*)Wb  + ((size_t)(ntile * 2) * NTK + ktbase) * PSTEP + o;
    const char* bHi = bLo + (size_t)NTK * PSTEP;

    #define STAGE(kt, sl) do {                                       \
        const size_t kk = (size_t)(kt) * PSTEP;                      \
        char* d = Sm + (size_t)(sl) * SLOT_B + o;                    \
        gl_lds16(aLo + kk, d);                                       \
        gl_lds16(aHi + kk, d + 8192);                                \
        gl_lds16(bLo + kk, d + 16384);                               \
        gl_lds16(bHi + kk, d + 24576);                               \
    } while (0)

    #define COMPUTE(sl) do {                                                  \
        const char* bA_ = Sm + (size_t)(sl) * SLOT_B;                         \
        const char* bB_ = bA_ + 16384;                                        \
        bf16x8 aF[4], bF[8];                                                  \
        _Pragma("unroll")                                                     \
        for (int m = 0; m < 4; ++m)                                           \
            aF[m] = *(const bf16x8*)(bA_ + (wr * 4 + m) * 1024 + lane * 16);  \
        _Pragma("unroll")                                                     \
        for (int n = 0; n < 8; ++n)                                           \
            bF[n] = *(const bf16x8*)(bB_ + (wn * 8 + n) * 1024 + lane * 16);  \
        __builtin_amdgcn_s_setprio(1);                                        \
        _Pragma("unroll")                                                     \
        for (int m = 0; m < 4; ++m)                                           \
            _Pragma("unroll")                                                 \
            for (int n = 0; n < 8; ++n)                                       \
                acc[m][n] = __builtin_amdgcn_mfma_f32_16x16x32_bf16(          \
                                aF[m], bF[n], acc[m][n], 0, 0, 0);            \
        __builtin_amdgcn_s_setprio(0);                                        \
    } while (0)

    STAGE(0, 0);
    STAGE(1, 1);

    #pragma unroll 2
    for (int kt = 0; kt < ksteps - 2; ++kt) {
        STAGE(kt + 2, (kt + 2) & 3);
        asm volatile("s_waitcnt vmcnt(8) lgkmcnt(0)" ::: "memory");  // tile kt landed
        __builtin_amdgcn_s_barrier();
        COMPUTE(kt & 3);
    }
    asm volatile("s_waitcnt vmcnt(4) lgkmcnt(0)" ::: "memory");
    __builtin_amdgcn_s_barrier();
    COMPUTE((ksteps - 2) & 3);
    asm volatile("s_waitcnt vmcnt(0) lgkmcnt(0)" ::: "memory");
    __builtin_amdgcn_s_barrier();
    COMPUTE((ksteps - 1) & 3);

    // ---- epilogue: direct store; C/D map col=lane&15, row=(lane>>4)*4+reg --
    const int m0 = mtile * BM, n0 = ntile * BN;
    #pragma unroll
    for (int m = 0; m < 4; ++m) {
        const int row = m0 + wr * 64 + m * 16 + kgrp * 4;
        #pragma unroll
        for (int n = 0; n < 8; ++n) {
            const int col = n0 + wn * 128 + n * 16 + frow;
            float* cp = Cout + (size_t)row * OUT_F + col;
            #pragma unroll
            for (int q = 0; q < 4; ++q)
                cp[(size_t)q * OUT_F] = acc[m][n][q];
        }
    }
    #undef STAGE
    #undef COMPUTE
}

// ---------------------------------------------------------------------------
__global__ __launch_bounds__(256)
void add_kernel(float* __restrict__ out, const float* __restrict__ P, int np) {
    const size_t i = (size_t)blockIdx.x * 256 + threadIdx.x;   // float4 index
    float4 a = ((const float4*)out)[i];
    for (int k = 0; k < np; ++k) {
        float4 b = ((const float4*)(P + (size_t)k * ((size_t)BATCH * OUT_F)))[i];
        a.x += b.x; a.y += b.y; a.z += b.z; a.w += b.w;
    }
    ((float4*)out)[i] = a;
}

// ---------------------------------------------------------------------------
extern "C" void kernel_launch(void* const* d_in, const int* in_sizes, int n_in,
                              void* d_out, int out_size, void* d_ws, size_t ws_size,
                              hipStream_t stream) {
    const float* x        = (const float*)d_in[0];
    const float* base_w   = (const float*)d_in[1];
    const float* spline_w = (const float*)d_in[2];
    const float* scaler   = (const float*)d_in[3];
    float* out = (float*)d_out;

    const size_t act_b = (size_t)BATCH * KTOT * 2;        // 75.5 MB
    const size_t wb_b  = (size_t)OUT_F * KTOT * 2;        // 18.9 MB
    const size_t ps    = (size_t)BATCH * OUT_F * 4;       // 16.8 MB per partial
    if (ws_size < act_b + wb_b) return;

    unsigned short* Act = (unsigned short*)d_ws;
    unsigned short* Wb  = (unsigned short*)((char*)d_ws + act_b);
    float*          P   = (float*)((char*)d_ws + act_b + wb_b);

    // adaptive split-K: ws >= 111.2MB (proven in r9) guarantees nsplit >= 2
    size_t avail = ws_size - act_b - wb_b;
    int np = (int)(avail / ps); if (np > 3) np = 3; if (np < 0) np = 0;
    const int nsplit = np + 1;             // 1,2,3,4 all divide 288
    const int ksteps = NTK / nsplit;

    build_all_kernel<<<5120, 256, 0, stream>>>(x, base_w, spline_w, scaler, Act, Wb);
    gemm_kernel<<<64 * nsplit, 512, 0, stream>>>(Act, Wb, out, P, ksteps);
    if (np > 0)
        add_kernel<<<(BATCH * OUT_F) / (256 * 4), 256, 0, stream>>>(out, P, np);
}